// Round 12
// baseline (177.621 us; speedup 1.0000x reference)
//
#include <hip/hip_runtime.h>
#include <hip/hip_bf16.h>
#include <math.h>

#define L_TAU_C 0.8f

typedef _Float16 half2_t __attribute__((ext_vector_type(2)));

union U32H2 { unsigned int u; half2_t h; };
__device__ __forceinline__ half2_t h2(unsigned int v) { U32H2 x; x.u = v; return x.h; }

__device__ __forceinline__ float sigmoidf_(float x) {
    return 1.0f / (1.0f + __expf(-x));
}

// ---------------------------------------------------------------------------
// Kernel 1: transpose x [128][4096][20] f32 -> xT [128][20][4096] f16.
// ---------------------------------------------------------------------------
__global__ __launch_bounds__(256) void k_transpose16(const float* __restrict__ x,
                                                     _Float16* __restrict__ xT) {
    int gp = blockIdx.x * 256 + threadIdx.x;      // 0..524287
    int b = gp >> 12, p = gp & 4095;
    const float4* src = reinterpret_cast<const float4*>(x + (size_t)gp * 20);
    float v[20];
#pragma unroll
    for (int k = 0; k < 5; ++k) {
        float4 q = src[k];
        v[4 * k + 0] = q.x; v[4 * k + 1] = q.y; v[4 * k + 2] = q.z; v[4 * k + 3] = q.w;
    }
    _Float16* dst = xT + (size_t)b * 20 * 4096 + p;
#pragma unroll
    for (int t = 0; t < 20; ++t) dst[(size_t)t * 4096] = (_Float16)v[t];
}

// ---------------------------------------------------------------------------
// Kernel 2: fused conv + SNU(s1,y1) + maxpool + partial FC dot.
// R9 barrierless no-LDS structure (378/384 thds, thread = 1 pool row x 2
// pool cols, 18 waves/CU) + the R10 load path DONE RIGHT:
//  * per conv row: 2 x dwordx4 + 1 dword, all 16B/4B-aligned from base
//    u32 ub = 2*pcg - 2*(pcg&1); window u32s selected by parity with
//    NAMED SCALAR cndmasks only (R10's w_[9] array folded to a runtime
//    GEP -> scratch-in-LDS, 590us; zero arrays on the select path here).
//  * rolling 2-row register prefetch (row xr+2 issued while xr consumed)
//    so ~2 rows of L1 loads are always in flight.
//  * E (9th u32) clamped in-row for pcg==13 (feeds only masked junk col).
// Weights in SGPRs (readfirstlane); fdot2 + v_alignbit datapath; per-wave
// partials straight to global. s[7]/ss[6] keep literal-after-unroll
// indices (R9-proven safe, VGPR 32).
// ---------------------------------------------------------------------------
template<int XMODE>   // 1 = f16 transposed input, 0 = strided f32 fallback
__global__ __launch_bounds__(384, 5) void k_conv_snu(
    const float* __restrict__ x,      // [128][4096][20]
    const _Float16* __restrict__ xT,  // [128][20][4096]
    const float* __restrict__ Wc,     // [6][1][10][10]
    const float* __restrict__ bc,     // [6]
    const float* __restrict__ W2,     // [4374][2]
    float* __restrict__ partw)        // [20][128][6][6][2]
{
    const int tid = threadIdx.x;
    const int bi = blockIdx.x;
    const int xcd = bi & 7, slot = bi >> 3;
    const int b = (slot / 6) * 8 + xcd;   // all 6 ch of b on same XCD
    const int ch = slot % 6;

    const bool active = tid < 378;
    const int r = tid / 14;           // pool row 0..26
    const int pcg = tid % 14;         // pool cols 2pcg, 2pcg+1
    const int row0 = 2 * r;
    const int off = pcg & 1;          // window parity
    const int ub = 2 * pcg - 2 * off; // 16B-aligned u32 base of window
    const int ue = (pcg == 13) ? 7 : 8;  // E u32 offset, clamped in-row

    // ---- weights -> SGPRs (one-time, uniform) ----
    const float* wb = Wc + ch * 100;
    unsigned int wsg[50];
#pragma unroll
    for (int i = 0; i < 50; ++i) {
        U32H2 pk;
        pk.h = half2_t{(_Float16)wb[2 * i], (_Float16)wb[2 * i + 1]};
        wsg[i] = (unsigned int)__builtin_amdgcn_readfirstlane((int)pk.u);
    }

    float s1[2][4], y1[2][4];
#pragma unroll
    for (int i = 0; i < 2; ++i)
#pragma unroll
        for (int j = 0; j < 4; ++j) { s1[i][j] = 0.f; y1[i][j] = 0.f; }

    const float bch = bc[ch];

    float w2r[2][2];
    w2r[0][0] = 0.f; w2r[0][1] = 0.f; w2r[1][0] = 0.f; w2r[1][1] = 0.f;
    if (active) {
#pragma unroll
        for (int k = 0; k < 2; ++k) {
            int pc = 2 * pcg + k;
            if (pc < 27) {
                int f0 = ch * 729 + r * 27 + pc;
                w2r[k][0] = W2[(size_t)f0 * 2 + 0];
                w2r[k][1] = W2[(size_t)f0 * 2 + 1];
            }
        }
    }

    const unsigned* xb16 = reinterpret_cast<const unsigned*>(
        xT + (size_t)b * 20 * 4096) + ub;          // u32 units
    const float* xb32 = x + (size_t)b * 4096 * 20 + (size_t)(2 * ub) * 20;

    for (int t = 0; t < 20; ++t) {
        float p0 = 0.f, p1 = 0.f;
        if (active) {
            float c0[4] = {0.f, 0.f, 0.f, 0.f};
            float c1[4] = {0.f, 0.f, 0.f, 0.f};

            const unsigned* tb16 = xb16 + (size_t)t * 2048;   // row stride 32 u32
            const float* tb32 = xb32 + t;

            // rolling 2-row prefetch (named regs, slot = xr&1)
            uint4 r0A, r0B, r1A, r1B; unsigned r0E, r1E;
            if (XMODE == 1) {
                const unsigned* rp0 = tb16 + (size_t)(row0 + 0) * 32;
                const unsigned* rp1 = tb16 + (size_t)(row0 + 1) * 32;
                r0A = *reinterpret_cast<const uint4*>(rp0);
                r0B = *reinterpret_cast<const uint4*>(rp0 + 4);
                r0E = rp0[ue];
                r1A = *reinterpret_cast<const uint4*>(rp1);
                r1B = *reinterpret_cast<const uint4*>(rp1 + 4);
                r1E = rp1[ue];
            } else {
#pragma unroll
                for (int sl = 0; sl < 2; ++sl) {
                    const float* rp = tb32 + (size_t)(row0 + sl) * 64 * 20;
                    uint4 A, Bq; unsigned E;
                    U32H2 pk;
                    pk.h = half2_t{(_Float16)rp[0],   (_Float16)rp[20]};  A.x = pk.u;
                    pk.h = half2_t{(_Float16)rp[40],  (_Float16)rp[60]};  A.y = pk.u;
                    pk.h = half2_t{(_Float16)rp[80],  (_Float16)rp[100]}; A.z = pk.u;
                    pk.h = half2_t{(_Float16)rp[120], (_Float16)rp[140]}; A.w = pk.u;
                    pk.h = half2_t{(_Float16)rp[160], (_Float16)rp[180]}; Bq.x = pk.u;
                    pk.h = half2_t{(_Float16)rp[200], (_Float16)rp[220]}; Bq.y = pk.u;
                    pk.h = half2_t{(_Float16)rp[240], (_Float16)rp[260]}; Bq.z = pk.u;
                    pk.h = half2_t{(_Float16)rp[280], (_Float16)rp[300]}; Bq.w = pk.u;
                    pk.h = half2_t{(_Float16)rp[ue * 40], (_Float16)rp[ue * 40 + 20]};
                    E = pk.u;
                    if (sl == 0) { r0A = A; r0B = Bq; r0E = E; }
                    else         { r1A = A; r1B = Bq; r1E = E; }
                }
            }

#pragma unroll
            for (int xr = 0; xr < 11; ++xr) {
                // consume slot (xr&1): SSA copies of named regs
                uint4 A  = (xr & 1) ? r1A : r0A;
                uint4 Bq = (xr & 1) ? r1B : r0B;
                unsigned E = (xr & 1) ? r1E : r0E;
                // prefetch row xr+2 into the freed slot
                if (xr + 2 <= 10) {
                    if (XMODE == 1) {
                        const unsigned* rp = tb16 + (size_t)(row0 + xr + 2) * 32;
                        uint4 nA = *reinterpret_cast<const uint4*>(rp);
                        uint4 nB = *reinterpret_cast<const uint4*>(rp + 4);
                        unsigned nE = rp[ue];
                        if (xr & 1) { r1A = nA; r1B = nB; r1E = nE; }
                        else        { r0A = nA; r0B = nB; r0E = nE; }
                    } else {
                        const float* rp = tb32 + (size_t)(row0 + xr + 2) * 64 * 20;
                        uint4 nA, nB; unsigned nE;
                        U32H2 pk;
                        pk.h = half2_t{(_Float16)rp[0],   (_Float16)rp[20]};  nA.x = pk.u;
                        pk.h = half2_t{(_Float16)rp[40],  (_Float16)rp[60]};  nA.y = pk.u;
                        pk.h = half2_t{(_Float16)rp[80],  (_Float16)rp[100]}; nA.z = pk.u;
                        pk.h = half2_t{(_Float16)rp[120], (_Float16)rp[140]}; nA.w = pk.u;
                        pk.h = half2_t{(_Float16)rp[160], (_Float16)rp[180]}; nB.x = pk.u;
                        pk.h = half2_t{(_Float16)rp[200], (_Float16)rp[220]}; nB.y = pk.u;
                        pk.h = half2_t{(_Float16)rp[240], (_Float16)rp[260]}; nB.z = pk.u;
                        pk.h = half2_t{(_Float16)rp[280], (_Float16)rp[300]}; nB.w = pk.u;
                        pk.h = half2_t{(_Float16)rp[ue * 40], (_Float16)rp[ue * 40 + 20]};
                        nE = pk.u;
                        if (xr & 1) { r1A = nA; r1B = nB; r1E = nE; }
                        else        { r0A = nA; r0B = nB; r0E = nE; }
                    }
                }

                // parity select: NAMED scalars only (no arrays -> no scratch)
                unsigned s0 = off ? A.z : A.x;
                unsigned s1v = off ? A.w : A.y;
                unsigned s2 = off ? Bq.x : A.z;
                unsigned s3 = off ? Bq.y : A.w;
                unsigned s4 = off ? Bq.z : Bq.x;
                unsigned s5 = off ? Bq.w : Bq.y;
                unsigned s6 = off ? E : Bq.z;
                unsigned s[7] = {s0, s1v, s2, s3, s4, s5, s6};
                unsigned ss[6];
#pragma unroll
                for (int i = 0; i < 6; ++i)
                    ss[i] = (s[i] >> 16) | (s[i + 1] << 16);   // v_alignbit

                if (xr <= 9) {
#pragma unroll
                    for (int m = 0; m < 5; ++m) {
                        half2_t w = h2(wsg[xr * 5 + m]);
                        c0[0] = __builtin_amdgcn_fdot2(h2(s[m]),      w, c0[0], false);
                        c0[1] = __builtin_amdgcn_fdot2(h2(ss[m]),     w, c0[1], false);
                        c0[2] = __builtin_amdgcn_fdot2(h2(s[m + 1]),  w, c0[2], false);
                        c0[3] = __builtin_amdgcn_fdot2(h2(ss[m + 1]), w, c0[3], false);
                    }
                }
                if (xr >= 1) {
#pragma unroll
                    for (int m = 0; m < 5; ++m) {
                        half2_t w = h2(wsg[(xr - 1) * 5 + m]);
                        c1[0] = __builtin_amdgcn_fdot2(h2(s[m]),      w, c1[0], false);
                        c1[1] = __builtin_amdgcn_fdot2(h2(ss[m]),     w, c1[1], false);
                        c1[2] = __builtin_amdgcn_fdot2(h2(s[m + 1]),  w, c1[2], false);
                        c1[3] = __builtin_amdgcn_fdot2(h2(ss[m + 1]), w, c1[3], false);
                    }
                }
            }
            // SNU: s = relu(c + 0.8*s*(1-y)); y = sigmoid(s + bc)
#pragma unroll
            for (int j = 0; j < 4; ++j) {
                float sa = fmaxf(c0[j] + L_TAU_C * s1[0][j] * (1.f - y1[0][j]), 0.f);
                float sb = fmaxf(c1[j] + L_TAU_C * s1[1][j] * (1.f - y1[1][j]), 0.f);
                s1[0][j] = sa; s1[1][j] = sb;
                y1[0][j] = sigmoidf_(sa + bch);
                y1[1][j] = sigmoidf_(sb + bch);
            }
            // maxpool 2x2 (2 pool outs) + partial FC dot
            float h0 = fmaxf(fmaxf(y1[0][0], y1[0][1]), fmaxf(y1[1][0], y1[1][1]));
            float h1 = fmaxf(fmaxf(y1[0][2], y1[0][3]), fmaxf(y1[1][2], y1[1][3]));
            p0 = h0 * w2r[0][0] + h1 * w2r[1][0];
            p1 = h0 * w2r[0][1] + h1 * w2r[1][1];
        }
        // wave reduce -> direct global store of per-wave partials
#pragma unroll
        for (int off2 = 32; off2 >= 1; off2 >>= 1) {
            p0 += __shfl_down(p0, off2);
            p1 += __shfl_down(p1, off2);
        }
        if ((tid & 63) == 0) {
            float2 val; val.x = p0; val.y = p1;
            *reinterpret_cast<float2*>(
                &partw[((((size_t)t * 128 + b) * 6 + ch) * 6 + (tid >> 6)) * 2]) = val;
        }
    }
}

// ---------------------------------------------------------------------------
// Kernel 3: s2/y2 recurrence, out_rec, m, loss, acc. One block, 128 threads.
// ---------------------------------------------------------------------------
__global__ __launch_bounds__(128) void k_final(const float* __restrict__ partw,
                                               const void* __restrict__ yraw,
                                               const float* __restrict__ b2,
                                               float* __restrict__ out) {
    __shared__ float red[4];
    const int b = threadIdx.x;  // 0..127

    const int* yi = (const int*)yraw;
    bool i64 = true;
    for (int k = 0; k < 64; ++k) {
        if (yi[2 * k + 1] != 0) { i64 = false; break; }
    }
    int lbl = i64 ? (int)((const long long*)yraw)[b] : yi[b];

    float b20 = b2[0], b21 = b2[1];
    float s20 = 0.f, s21 = 0.f, y20 = 0.f, y21 = 0.f, m0 = 0.f, m1 = 0.f;
    float* orec = out + 257 + b * 42;
    orec[0] = 0.f; orec[1] = 0.f;
    for (int t = 0; t < 20; ++t) {
        const float4* pp = reinterpret_cast<const float4*>(
            partw + ((size_t)t * 128 + b) * 72);
        float sum0 = 0.f, sum1 = 0.f;
#pragma unroll
        for (int i = 0; i < 18; ++i) {
            float4 a = pp[i];
            sum0 += a.x + a.z;
            sum1 += a.y + a.w;
        }
        s20 = fmaxf(sum0 + L_TAU_C * s20 * (1.f - y20), 0.f);
        s21 = fmaxf(sum1 + L_TAU_C * s21 * (1.f - y21), 0.f);
        y20 = sigmoidf_(s20 + b20);
        y21 = sigmoidf_(s21 + b21);
        orec[(t + 1) * 2 + 0] = y20;
        orec[(t + 1) * 2 + 1] = y21;
        m0 += y20; m1 += y21;
    }
    m0 *= 0.05f; m1 *= 0.05f;
    out[1 + b * 2 + 0] = m0;
    out[1 + b * 2 + 1] = m1;

    float mx = fmaxf(m0, m1);
    float lse = mx + logf(expf(m0 - mx) + expf(m1 - mx));
    float lossc = -(((lbl != 0) ? m1 : m0) - lse);
    int pred = (m1 > m0) ? 1 : 0;
    float accc = (pred == lbl) ? 1.f : 0.f;
#pragma unroll
    for (int off = 32; off >= 1; off >>= 1) {
        lossc += __shfl_down(lossc, off);
        accc += __shfl_down(accc, off);
    }
    if ((b & 63) == 0) { red[(b >> 6) * 2] = lossc; red[(b >> 6) * 2 + 1] = accc; }
    __syncthreads();
    if (b == 0) {
        out[0] = (red[0] + red[2]) * (1.f / 128.f);
        out[5633] = (red[1] + red[3]) * (1.f / 128.f);
    }
}

extern "C" void kernel_launch(void* const* d_in, const int* in_sizes, int n_in,
                              void* d_out, int out_size, void* d_ws, size_t ws_size,
                              hipStream_t stream) {
    const float* x  = (const float*)d_in[0];
    const void*  y  = d_in[1];
    const float* Wc = (const float*)d_in[2];
    const float* bc = (const float*)d_in[3];
    const float* W2 = (const float*)d_in[4];
    const float* b2 = (const float*)d_in[5];
    float* out = (float*)d_out;

    const size_t xt_bytes = (size_t)128 * 20 * 4096 * 2;         // 20,971,520
    const size_t partw_bytes = (size_t)20 * 128 * 6 * 6 * 2 * 4; // 737,280
    const int use16 = (ws_size >= xt_bytes + partw_bytes) ? 1 : 0;

    _Float16* xT = (_Float16*)d_ws;
    float* partw = use16 ? (float*)((char*)d_ws + xt_bytes) : (float*)d_ws;

    if (use16) {
        k_transpose16<<<2048, 256, 0, stream>>>(x, xT);
        k_conv_snu<1><<<768, 384, 0, stream>>>(x, xT, Wc, bc, W2, partw);
    } else {
        k_conv_snu<0><<<768, 384, 0, stream>>>(x, (const _Float16*)d_ws, Wc, bc, W2, partw);
    }
    k_final<<<1, 128, 0, stream>>>(partw, y, b2, out);
}

// Round 13
// 163.374 us; speedup vs baseline: 1.0872x; 1.0872x over previous
//
#include <hip/hip_runtime.h>
#include <hip/hip_bf16.h>
#include <math.h>

#define L_TAU_C 0.8f

typedef _Float16 f16x8 __attribute__((ext_vector_type(8)));
typedef float f32x4 __attribute__((ext_vector_type(4)));
typedef unsigned int uint2a4 __attribute__((ext_vector_type(2), aligned(4)));
typedef unsigned int uint4e __attribute__((ext_vector_type(4)));

union U4H8 { uint4e u; f16x8 h; };
typedef _Float16 half2_t __attribute__((ext_vector_type(2)));
union U32H2 { unsigned int u; half2_t h; };

__device__ __forceinline__ float sigmoidf_(float x) {
    return 1.0f / (1.0f + __expf(-x));
}

// ---------------------------------------------------------------------------
// Kernel 1: transpose x [128][4096][20] f32 -> xT [128][20][4096] f16.
// ---------------------------------------------------------------------------
__global__ __launch_bounds__(256) void k_transpose16(const float* __restrict__ x,
                                                     _Float16* __restrict__ xT) {
    int gp = blockIdx.x * 256 + threadIdx.x;      // 0..524287
    int b = gp >> 12, p = gp & 4095;
    const float4* src = reinterpret_cast<const float4*>(x + (size_t)gp * 20);
    float v[20];
#pragma unroll
    for (int k = 0; k < 5; ++k) {
        float4 q = src[k];
        v[4 * k + 0] = q.x; v[4 * k + 1] = q.y; v[4 * k + 2] = q.z; v[4 * k + 3] = q.w;
    }
    _Float16* dst = xT + (size_t)b * 20 * 4096 + p;
#pragma unroll
    for (int t = 0; t < 20; ++t) dst[(size_t)t * 4096] = (_Float16)v[t];
}

// ---------------------------------------------------------------------------
// Kernel 2: MFMA implicit-GEMM conv + SNU(s1,y1) + maxpool + partial FC dot.
// Cross-round evidence (R9/R11/R12): the dot2 family is instruction-issue
// bound (~900 VALU/thread/t). mfma_f32_16x16x32_f16 = 512 FLOP/instr vs
// dot2's 4 -> collapse the conv into 15 MFMA + 10 loads per wave per t.
//
// Implicit GEMM: M = 16 conv rows (strip), K = 160 (10 win rows x 16 win
// cols, 5 K32 slices), N = 16 = (ch 0..7) x (col offset parity e); three
// B-sets s (d = 2s+e) reuse ONE A to produce output cols C0..C0+5.
// A fragment (lane l, slice q): elems 0-3 = x[RS+(l&15)+2q][C0+4*(l>>4)+j],
// elems 4-7 = same at row +1 (two 8B loads, 4B-aligned).
// B built once per block from Wc (exec-masked per-lane gathers).
// D (m89-verified): lane holds rows 4*(l>>4)+reg, col n=l&15 -> SNU state
// per lane = 3 sets x 4 rows; pool row-pairs in-lane, col-pairs via
// shfl_xor(1); FC weights masked (e==1 / ch>=6 / pool_row>26 -> 0).
// Row clamp min(.,63) keeps strip-3 garbage reads in-tile (finite, masked).
// Grid 1152 = 128 b x 9 col-groups (XCD-swizzled), 4 waves = 4 row strips.
// Barrierless, no LDS. Per-wave partials straight to global.
// ---------------------------------------------------------------------------
template<int XMODE>   // 1 = f16 transposed input, 0 = strided f32 fallback
__global__ __launch_bounds__(256, 3) void k_conv_snu(
    const float* __restrict__ x,      // [128][4096][20]
    const _Float16* __restrict__ xT,  // [128][20][4096]
    const float* __restrict__ Wc,     // [6][1][10][10]
    const float* __restrict__ bc,     // [6]
    const float* __restrict__ W2,     // [4374][2]
    float* __restrict__ partw)        // [20][128][9][4][2]
{
    const int tid = threadIdx.x;
    const int bi = blockIdx.x;                 // 0..1151
    const int xcd = bi & 7, slot = bi >> 3;    // slot 0..143
    const int b = (slot / 9) * 8 + xcd;        // all 9 jg of b on same XCD
    const int jg = slot % 9;                   // conv cols 6jg..6jg+5
    const int w = tid >> 6;                    // wave = row strip 0..3
    const int l = tid & 63;
    const int RS = 16 * w;                     // strip conv-row base
    const int C0 = 6 * jg;
    const int n = l & 15, lh = l >> 4;
    const int ch = n >> 1, e = n & 1;

    // ---- B fragments: built once, constant over t ----
    f16x8 Bf[3][5];
#pragma unroll
    for (int s = 0; s < 3; ++s) {
#pragma unroll
        for (int q = 0; q < 5; ++q) {
            f16x8 bv;
#pragma unroll
            for (int j = 0; j < 8; ++j) {
                int wr = 2 * q + (j >> 2);
                int wc = 4 * lh + (j & 3);
                int wcd = wc - (2 * s + e);
                float wv = 0.f;
                if (ch < 6 && wcd >= 0 && wcd < 10)
                    wv = Wc[ch * 100 + wr * 10 + wcd];
                bv[j] = (_Float16)wv;
            }
            Bf[s][q] = bv;
        }
    }

    // ---- SNU state (3 sets x 4 rows per lane) ----
    float sA[3][4], yA[3][4];
#pragma unroll
    for (int s = 0; s < 3; ++s)
#pragma unroll
        for (int g = 0; g < 4; ++g) { sA[s][g] = 0.f; yA[s][g] = 0.f; }

    const float bch = (ch < 6) ? bc[ch] : 0.f;

    // ---- FC weights, fully masked ----
    float w2v[3][2][2];
#pragma unroll
    for (int s = 0; s < 3; ++s)
#pragma unroll
        for (int m = 0; m < 2; ++m) {
            int prow = 8 * w + 2 * lh + m;
            int pcol = 3 * jg + s;
            float a0 = 0.f, a1 = 0.f;
            if (e == 0 && ch < 6 && prow < 27) {
                int f = ch * 729 + prow * 27 + pcol;
                a0 = W2[(size_t)f * 2 + 0];
                a1 = W2[(size_t)f * 2 + 1];
            }
            w2v[s][m][0] = a0; w2v[s][m][1] = a1;
        }

    const _Float16* xb16 = xT + (size_t)b * 20 * 4096;
    const float* xb32 = x + (size_t)b * 4096 * 20;
    const int ar = RS + (l & 15);        // A-matrix row -> conv row
    const int acol = C0 + 4 * lh;        // window col base for this lane

    for (int t = 0; t < 20; ++t) {
        // ---- load A fragments (5 slices x 2 x 8B) ----
        f16x8 Af[5];
        if (XMODE == 1) {
            const _Float16* tb = xb16 + (size_t)t * 4096 + acol;
#pragma unroll
            for (int q = 0; q < 5; ++q) {
                int r0 = ar + 2 * q;     if (r0 > 63) r0 = 63;
                int r1 = ar + 2 * q + 1; if (r1 > 63) r1 = 63;
                uint2a4 lo = *reinterpret_cast<const uint2a4*>(tb + r0 * 64);
                uint2a4 hi = *reinterpret_cast<const uint2a4*>(tb + r1 * 64);
                U4H8 u; u.u = (uint4e){lo[0], lo[1], hi[0], hi[1]};
                Af[q] = u.h;
            }
        } else {
            const float* tb = xb32 + t;
#pragma unroll
            for (int q = 0; q < 5; ++q) {
                f16x8 av;
#pragma unroll
                for (int j = 0; j < 8; ++j) {
                    int r = ar + 2 * q + (j >> 2); if (r > 63) r = 63;
                    av[j] = (_Float16)tb[(size_t)(r * 64 + acol + (j & 3)) * 20];
                }
                Af[q] = av;
            }
        }

        // ---- 15 MFMA: 3 B-sets over shared A ----
        f32x4 acc[3];
#pragma unroll
        for (int s = 0; s < 3; ++s) acc[s] = (f32x4){0.f, 0.f, 0.f, 0.f};
#pragma unroll
        for (int q = 0; q < 5; ++q) {
#pragma unroll
            for (int s = 0; s < 3; ++s)
                acc[s] = __builtin_amdgcn_mfma_f32_16x16x32_f16(
                    Af[q], Bf[s][q], acc[s], 0, 0, 0);
        }

        // ---- SNU + pool + FC ----
        float p0 = 0.f, p1 = 0.f;
#pragma unroll
        for (int s = 0; s < 3; ++s) {
#pragma unroll
            for (int g = 0; g < 4; ++g) {
                float sa = fmaxf(acc[s][g] + L_TAU_C * sA[s][g] * (1.f - yA[s][g]), 0.f);
                sA[s][g] = sa;
                yA[s][g] = sigmoidf_(sa + bch);
            }
            float m0 = fmaxf(yA[s][0], yA[s][1]);
            float m1 = fmaxf(yA[s][2], yA[s][3]);
            float o0 = __shfl_xor(m0, 1);
            float o1 = __shfl_xor(m1, 1);
            float h0 = fmaxf(m0, o0);
            float h1 = fmaxf(m1, o1);
            p0 += h0 * w2v[s][0][0] + h1 * w2v[s][1][0];
            p1 += h0 * w2v[s][0][1] + h1 * w2v[s][1][1];
        }

        // ---- wave reduce -> global partials ----
#pragma unroll
        for (int off = 32; off >= 1; off >>= 1) {
            p0 += __shfl_down(p0, off);
            p1 += __shfl_down(p1, off);
        }
        if (l == 0) {
            float2 val; val.x = p0; val.y = p1;
            *reinterpret_cast<float2*>(
                &partw[((((size_t)t * 128 + b) * 9 + jg) * 4 + w) * 2]) = val;
        }
    }
}

// ---------------------------------------------------------------------------
// Kernel 3: s2/y2 recurrence, out_rec, m, loss, acc. One block, 128 threads.
// ---------------------------------------------------------------------------
__global__ __launch_bounds__(128) void k_final(const float* __restrict__ partw,
                                               const void* __restrict__ yraw,
                                               const float* __restrict__ b2,
                                               float* __restrict__ out) {
    __shared__ float red[4];
    const int b = threadIdx.x;  // 0..127

    const int* yi = (const int*)yraw;
    bool i64 = true;
    for (int k = 0; k < 64; ++k) {
        if (yi[2 * k + 1] != 0) { i64 = false; break; }
    }
    int lbl = i64 ? (int)((const long long*)yraw)[b] : yi[b];

    float b20 = b2[0], b21 = b2[1];
    float s20 = 0.f, s21 = 0.f, y20 = 0.f, y21 = 0.f, m0 = 0.f, m1 = 0.f;
    float* orec = out + 257 + b * 42;
    orec[0] = 0.f; orec[1] = 0.f;
    for (int t = 0; t < 20; ++t) {
        const float4* pp = reinterpret_cast<const float4*>(
            partw + ((size_t)t * 128 + b) * 72);
        float sum0 = 0.f, sum1 = 0.f;
#pragma unroll
        for (int i = 0; i < 18; ++i) {
            float4 a = pp[i];
            sum0 += a.x + a.z;
            sum1 += a.y + a.w;
        }
        s20 = fmaxf(sum0 + L_TAU_C * s20 * (1.f - y20), 0.f);
        s21 = fmaxf(sum1 + L_TAU_C * s21 * (1.f - y21), 0.f);
        y20 = sigmoidf_(s20 + b20);
        y21 = sigmoidf_(s21 + b21);
        orec[(t + 1) * 2 + 0] = y20;
        orec[(t + 1) * 2 + 1] = y21;
        m0 += y20; m1 += y21;
    }
    m0 *= 0.05f; m1 *= 0.05f;
    out[1 + b * 2 + 0] = m0;
    out[1 + b * 2 + 1] = m1;

    float mx = fmaxf(m0, m1);
    float lse = mx + logf(expf(m0 - mx) + expf(m1 - mx));
    float lossc = -(((lbl != 0) ? m1 : m0) - lse);
    int pred = (m1 > m0) ? 1 : 0;
    float accc = (pred == lbl) ? 1.f : 0.f;
#pragma unroll
    for (int off = 32; off >= 1; off >>= 1) {
        lossc += __shfl_down(lossc, off);
        accc += __shfl_down(accc, off);
    }
    if ((b & 63) == 0) { red[(b >> 6) * 2] = lossc; red[(b >> 6) * 2 + 1] = accc; }
    __syncthreads();
    if (b == 0) {
        out[0] = (red[0] + red[2]) * (1.f / 128.f);
        out[5633] = (red[1] + red[3]) * (1.f / 128.f);
    }
}

extern "C" void kernel_launch(void* const* d_in, const int* in_sizes, int n_in,
                              void* d_out, int out_size, void* d_ws, size_t ws_size,
                              hipStream_t stream) {
    const float* x  = (const float*)d_in[0];
    const void*  y  = d_in[1];
    const float* Wc = (const float*)d_in[2];
    const float* bc = (const float*)d_in[3];
    const float* W2 = (const float*)d_in[4];
    const float* b2 = (const float*)d_in[5];
    float* out = (float*)d_out;

    const size_t xt_bytes = (size_t)128 * 20 * 4096 * 2;         // 20,971,520
    const size_t partw_bytes = (size_t)20 * 128 * 9 * 4 * 2 * 4; // 737,280
    const int use16 = (ws_size >= xt_bytes + partw_bytes) ? 1 : 0;

    _Float16* xT = (_Float16*)d_ws;
    float* partw = use16 ? (float*)((char*)d_ws + xt_bytes) : (float*)d_ws;

    if (use16) {
        k_transpose16<<<2048, 256, 0, stream>>>(x, xT);
        k_conv_snu<1><<<1152, 256, 0, stream>>>(x, xT, Wc, bc, W2, partw);
    } else {
        k_conv_snu<0><<<1152, 256, 0, stream>>>(x, (const _Float16*)d_ws, Wc, bc, W2, partw);
    }
    k_final<<<1, 128, 0, stream>>>(partw, y, b2, out);
}